// Round 6
// baseline (528.988 us; speedup 1.0000x reference)
//
#include <hip/hip_runtime.h>

#define DEG 16
#define DD  128
#define KT  10      // template nodes (K)
#define TT  10      // templates
#define MM  17      // m = DEG+1
#define NPB 4       // nodes per block
#define THREADS 640 // 10 waves: wave w <-> template w
#define PITCH 132   // Fi row pitch in floats
#define EMS 11      // eM_own LDS stride (coprime with 32 -> conflict-free)

#if __has_builtin(__builtin_amdgcn_exp2f)
#define FEXP2(x) __builtin_amdgcn_exp2f(x)
#else
#define FEXP2(x) exp2f(x)
#endif

#if __has_builtin(__builtin_amdgcn_rcpf)
#define FRCP(x) __builtin_amdgcn_rcpf(x)
#else
#define FRCP(x) (1.0f / (x))
#endif

#if __has_builtin(__builtin_amdgcn_logf)
#define FLOG2(x) __builtin_amdgcn_logf(x)
#else
#define FLOG2(x) __log2f(x)
#endif

// (1/EPS)*log2(e), EPS = 0.5
#define TWO_LOG2E 2.8853900817779268f
// log2(e): scale for the hoisted exp2 of 0.5*Mc
#define NLOG2E    1.4426950408889634f
// EPS*ln2 = 1/TWO_LOG2E: recovers 0.5*Mc from log2(eM)
#define EPSLN2    0.34657359027997264f
// QP = qw/pw = 17/10 folded into the 2-wide u-update: RQP = 1/QP = 10/17
#define RQP       0.5882352941176471f
// vv'' initial value = 1/QP
#define VV0       0.5882352941176471f
// pw*QP = (1/17)*(17/10) = 1/10 exactly
#define PWQP      0.1f

typedef float v2f __attribute__((ext_vector_type(2)));
typedef float v4f __attribute__((ext_vector_type(4)));

// packed fp32 fma (VGPR operands only; R3's "s"-pin caused SGPR pressure)
__device__ __forceinline__ v2f pk_fma(v2f a, v2f b, v2f c) {
    asm("v_pk_fma_f32 %0, %1, %2, %0" : "+v"(c) : "v"(a), "v"(b));
    return c;
}

// builtin-based 16-lane sum for the final objective
template <int CTRL>
__device__ __forceinline__ float dpp_add(float x) {
    union { float f; int i; } a, b;
    a.f = x;
    b.i = __builtin_amdgcn_update_dpp(0, a.i, CTRL, 0xF, 0xF, true);
    return x + b.f;
}
__device__ __forceinline__ float sum16(float t) {
    t = dpp_add<0xB1>(t);
    t = dpp_add<0x4E>(t);
    t = dpp_add<0x124>(t);
    t = dpp_add<0x128>(t);
    return t;
}

// hand-fused multi-value 16-lane butterflies (v_add_f32_dpp).
// VALU->DPP hazard needs 2 wait states: entry s_nop 1; interior spacing >=4.
#define _D(i, CTRL) "v_add_f32_dpp %" #i ", %" #i ", %" #i " " CTRL \
                    " row_mask:0xf bank_mask:0xf bound_ctrl:0\n\t"
#define _C1 "quad_perm:[1,0,3,2]"
#define _C2 "quad_perm:[2,3,0,1]"
#define _C3 "row_ror:4"
#define _C4 "row_ror:8"

__device__ __forceinline__ void sum16x6(float& a0, float& a1, float& a2,
                                        float& a3, float& a4, float& a5) {
    asm("s_nop 1\n\t"
        _D(0,_C1) _D(1,_C1) _D(2,_C1) _D(3,_C1) _D(4,_C1) _D(5,_C1)
        _D(0,_C2) _D(1,_C2) _D(2,_C2) _D(3,_C2) _D(4,_C2) _D(5,_C2)
        _D(0,_C3) _D(1,_C3) _D(2,_C3) _D(3,_C3) _D(4,_C3) _D(5,_C3)
        _D(0,_C4) _D(1,_C4) _D(2,_C4) _D(3,_C4) _D(4,_C4) _D(5,_C4)
        : "+v"(a0), "+v"(a1), "+v"(a2), "+v"(a3), "+v"(a4), "+v"(a5));
}

__device__ __forceinline__ void sum16x5(float& a0, float& a1, float& a2,
                                        float& a3, float& a4) {
    asm("s_nop 1\n\t"
        _D(0,_C1) _D(1,_C1) _D(2,_C1) _D(3,_C1) _D(4,_C1)
        _D(0,_C2) _D(1,_C2) _D(2,_C2) _D(3,_C2) _D(4,_C2)
        _D(0,_C3) _D(1,_C3) _D(2,_C3) _D(3,_C3) _D(4,_C3)
        _D(0,_C4) _D(1,_C4) _D(2,_C4) _D(3,_C4) _D(4,_C4)
        : "+v"(a0), "+v"(a1), "+v"(a2), "+v"(a3), "+v"(a4));
}

// Layout: wave w <-> template w; 64 lanes = 4 node-slots (p) x 16 lanes.
// Lane l owns row j=l+1; row 0 is register-replicated across the group.
// Phase order minimizes peak VGPR demand so NATURAL allocation (no occupancy
// attribute!) lands <=64 VGPR with zero spills:
//   mini-pass (row0/template norms) -> sE0,sNft (small separate LDS) -> freed
//   main M-pass (dotv only)         -> barrier -> eM_own into dead sFi
//   Sinkhorn (TKo/TK0/vv hot, eM streamed from LDS)
// NOTE: __launch_bounds__(,8) / amdgpu_waves_per_eu(8) both made the backend
// clamp VGPRs to 32 and spill ~70-350MB per dispatch (R3-R5). Do not re-add.
__global__ __launch_bounds__(THREADS)
void ltfgw_kernel(
    const float* __restrict__ x,      // [N,128]
    const int*   __restrict__ ei,     // edge_index[0], [N*DEG]
    const float* __restrict__ tmpl,   // [T,K,K]
    const float* __restrict__ tf,     // [T,K,128]
    float* __restrict__ out,          // [N,T]
    int N)
{
    constexpr int SLAB = MM * PITCH;     // 2244 floats per node
    __shared__ float sFi[NPB * SLAB];    // 35904 B; dead after M-pass -> eM_own
    __shared__ float sE0[TT * NPB * KT]; // 1600 B: eM0 per (wave, node-slot)
    __shared__ float sNft[TT * KT];      // 400 B: exp2(-log2e*nft/DD) per wave

    const int tid = threadIdx.x;
    const int b0  = blockIdx.x * NPB;

    // ---- stage Fi
    {
        const int kq = tid & 31;
        for (int r = tid >> 5; r < NPB * MM; r += (THREADS >> 5)) {
            int p = r / MM, j = r % MM;
            int node = b0 + p;
            if (node < N) {
                int src = (j == 0) ? node : ei[node * DEG + (j - 1)];
                float4 v4 = *(const float4*)(x + (size_t)src * DD + kq * 4);
                *(float4*)(&sFi[p * SLAB + j * PITCH + kq * 4]) = v4;
            }
        }
    }
    __syncthreads();

    const int w     = tid >> 6;
    const int wu    = __builtin_amdgcn_readfirstlane(w);
    const int lane  = tid & 63;
    const int p     = lane >> 4;
    const int l     = lane & 15;
    const int gbase = lane & ~15;
    const int node  = b0 + p;

    const int cl = (l < KT) ? l : 0;
    // Ct row base for column cl (8B-aligned: 40-byte row stride)
    const float* ctp = tmpl + ((size_t)wu * KT + cl) * KT;
    const float* tw  = tf + (size_t)wu * KT * DD;   // wave-uniform

    // ---- ct2q = (Ct^2 @ q)[cl]
    float ct2q;
    {
        v2f r0 = *(const v2f*)(ctp);
        v2f r1 = *(const v2f*)(ctp + 2);
        v2f r2 = *(const v2f*)(ctp + 4);
        v2f r3 = *(const v2f*)(ctp + 6);
        v2f r4 = *(const v2f*)(ctp + 8);
        v2f acc = pk_fma(r0, r0, (v2f){0.f, 0.f});
        acc = pk_fma(r1, r1, acc);
        acc = pk_fma(r2, r2, acc);
        acc = pk_fma(r3, r3, acc);
        acc = pk_fma(r4, r4, acc);
        ct2q = (acc.x + acc.y) * (1.f / KT);
    }

    // ---- mini-pass FIRST: row 0 dots + template norms + row0 norm
    // (k-distributed: lane l covers k in [8l, 8l+8), then 16-lane reduce).
    // Products go straight to LDS; dot0/nft/n0p registers are then free
    // before the register-heavy main pass begins.
    {
        float dot0[KT], nft[KT], n0p;
        const float* row0 = &sFi[p * SLAB + 8 * l];
        v4f z0 = *(const v4f*)(row0);
        v4f z1 = *(const v4f*)(row0 + 4);
        v2f nn = pk_fma(z0.lo, z0.lo, (v2f){0.f, 0.f});
        nn = pk_fma(z0.hi, z0.hi, nn);
        nn = pk_fma(z1.lo, z1.lo, nn);
        nn = pk_fma(z1.hi, z1.hi, nn);
        n0p = nn.x + nn.y;
#pragma unroll
        for (int c = 0; c < KT; ++c) {
            const float* tr = tw + c * DD + 8 * l;   // coalesced across lanes
            v4f t0_ = *(const v4f*)(tr);
            v4f t1_ = *(const v4f*)(tr + 4);
            v2f d = pk_fma(z0.lo, t0_.lo, (v2f){0.f, 0.f});
            d = pk_fma(z0.hi, t0_.hi, d);
            d = pk_fma(z1.lo, t1_.lo, d);
            d = pk_fma(z1.hi, t1_.hi, d);
            dot0[c] = d.x + d.y;
            v2f nf = pk_fma(t0_.lo, t0_.lo, (v2f){0.f, 0.f});
            nf = pk_fma(t0_.hi, t0_.hi, nf);
            nf = pk_fma(t1_.lo, t1_.lo, nf);
            nf = pk_fma(t1_.hi, t1_.hi, nf);
            nft[c] = nf.x + nf.y;
        }
        sum16x6(dot0[0], dot0[1], dot0[2], dot0[3], dot0[4], dot0[5]);
        sum16x5(dot0[6], dot0[7], dot0[8], dot0[9], n0p);
        sum16x5(nft[0], nft[1], nft[2], nft[3], nft[4]);
        sum16x5(nft[5], nft[6], nft[7], nft[8], nft[9]);

        // eM0 = exp2(-log2e * Mc0): one writer per 16-lane group (same wave
        // reads it later -> no barrier needed, lgkmcnt ordering suffices)
        if (l == 0) {
            float* e0p = &sE0[(w * NPB + p) * KT];
#pragma unroll
            for (int c = 0; c < KT; ++c) {
                float mc0 = (n0p + nft[c] - 2.f * dot0[c]) * (1.f / DD);
                e0p[c] = FEXP2(-NLOG2E * mc0);
            }
        }
        // eNft = exp2(-log2e*nft/DD), wave-uniform: one writer per wave
        if (lane == 0) {
            float* np_ = &sNft[w * KT];
#pragma unroll
            for (int c = 0; c < KT; ++c)
                np_[c] = FEXP2(-NLOG2E * nft[c] * (1.f / DD));
        }
    }

    // ---- M main pass: own row (LDS) vs 10 template rows (vector loads,
    // same address across all 64 lanes -> one L1 line broadcast)
    const float* myrow = &sFi[p * SLAB + (l + 1) * PITCH];
    v2f dotv[KT];
#pragma unroll
    for (int c = 0; c < KT; ++c) dotv[c] = (v2f){0.f, 0.f};
    v2f nrmv = (v2f){0.f, 0.f};
    for (int kk = 0; kk < DD; kk += 4) {
        v4f a4 = *(const v4f*)(myrow + kk);
        nrmv = pk_fma(a4.lo, a4.lo, nrmv);
        nrmv = pk_fma(a4.hi, a4.hi, nrmv);
#pragma unroll
        for (int c = 0; c < KT; ++c) {
            v4f f4 = *(const v4f*)(tw + c * DD + kk);
            dotv[c] = pk_fma(a4.lo, f4.lo, dotv[c]);
            dotv[c] = pk_fma(a4.hi, f4.hi, dotv[c]);
        }
    }
    float nrm_own = nrmv.x + nrmv.y;

    // ---- all sFi reads complete everywhere; reuse the buffer for eM_own
    __syncthreads();

    float* myEM = &sFi[tid * EMS];                 // stride 11: conflict-free
    const float* eNft = &sNft[w * KT];             // broadcast reads
    const float* gEM0 = &sE0[(w * NPB + p) * KT];  // broadcast within group
#pragma unroll
    for (int c = 0; c < KT; ++c) {
        float ex = FEXP2(-NLOG2E * (nrm_own - 2.f * (dotv[c].x + dotv[c].y))
                         * (1.f / DD));
        myEM[c] = ex * eNft[c];   // == exp2(-log2e * Mc_own[c]) up to 1 ulp
    }

    // ---- proximal Sinkhorn. TKo/TK0 hold Tp at outer boundaries, eK inside.
    float TKo[KT], TK0[KT], vv[KT];
#pragma unroll
    for (int c = 0; c < KT; ++c) {
        TKo[c] = 1.f / (MM * KT);
        TK0[c] = 1.f / (MM * KT);
    }
    float u_own = 0.f, u0 = 0.f;

#pragma unroll 1
    for (int outer = 0; outer < 5; ++outer) {
        // s[c] = 16-lane sum of Tp over neighbor rows
        float s[KT];
#pragma unroll
        for (int c = 0; c < KT; ++c) s[c] = TKo[c];
        sum16x5(s[0], s[1], s[2], s[3], s[4]);
        sum16x5(s[5], s[6], s[7], s[8], s[9]);

        // Ct row reload (L1-resident, 5x8B) + distributed Cs/C0 on column cl
        v2f r0 = *(const v2f*)(ctp);
        v2f r1 = *(const v2f*)(ctp + 2);
        v2f r2 = *(const v2f*)(ctp + 4);
        v2f r3 = *(const v2f*)(ctp + 6);
        v2f r4 = *(const v2f*)(ctp + 8);
        float Cs, C0;
        {
            float a = r0.x * s[0],   b = r0.y * s[1];
            a = fmaf(r1.x, s[2], a); b = fmaf(r1.y, s[3], b);
            a = fmaf(r2.x, s[4], a); b = fmaf(r2.y, s[5], b);
            a = fmaf(r3.x, s[6], a); b = fmaf(r3.y, s[7], b);
            a = fmaf(r4.x, s[8], a); b = fmaf(r4.y, s[9], b);
            Cs = a + b;
            float q = r0.x * TK0[0],   d = r0.y * TK0[1];
            q = fmaf(r1.x, TK0[2], q); d = fmaf(r1.y, TK0[3], d);
            q = fmaf(r2.x, TK0[4], q); d = fmaf(r2.y, TK0[5], d);
            q = fmaf(r3.x, TK0[6], q); d = fmaf(r3.y, TK0[7], d);
            q = fmaf(r4.x, TK0[8], q); d = fmaf(r4.y, TK0[9], d);
            C0 = q + d;
        }
        float e0 = FEXP2(-TWO_LOG2E * ((16.f / 17.f) + ct2q - 2.f * Cs));
        float e1 = FEXP2(-TWO_LOG2E * ((1.f  / 17.f) + ct2q - 2.f * C0));

        // Tp -> eK in place (eM factors streamed from LDS)
#pragma unroll
        for (int c = 0; c < KT; ++c) {
            float E1c = __shfl(e1, gbase + c, 64);
            TKo[c] = TKo[c] * (myEM[c] * E1c);
            float E0c = __shfl(e0, gbase + c, 64);
            TK0[c] = TK0[c] * (gEM0[c] * E0c);
            vv[c] = VV0;   // vv'' = vv/QP
        }

        // 10 Sinkhorn iterations in the vv''-scaled domain:
        //   u = RQP * rcp(sum_c eK*vv'');  vv'' = rcp(sum_rows eK*u)
#pragma unroll 1
        for (int it = 0; it < 10; ++it) {
            float ra = TKo[0] * vv[0], rb = TKo[1] * vv[1];
            float qa = TK0[0] * vv[0], qb = TK0[1] * vv[1];
#pragma unroll
            for (int c = 2; c < KT; c += 2) {
                ra = fmaf(TKo[c],     vv[c],     ra);
                rb = fmaf(TKo[c + 1], vv[c + 1], rb);
                qa = fmaf(TK0[c],     vv[c],     qa);
                qb = fmaf(TK0[c + 1], vv[c + 1], qb);
            }
            u_own = RQP * FRCP(ra + rb);
            u0    = RQP * FRCP(qa + qb);
            float t[KT];
#pragma unroll
            for (int c = 0; c < KT; ++c) t[c] = TKo[c] * u_own;
            sum16x5(t[0], t[1], t[2], t[3], t[4]);
            sum16x5(t[5], t[6], t[7], t[8], t[9]);
#pragma unroll
            for (int c = 0; c < KT; ++c)
                vv[c] = FRCP(fmaf(TK0[c], u0, t[c]));
        }

        // eK -> Tp in place: Tp = (pw*QP) * u * eK * vv''
        float puw = PWQP * u_own, pu0 = PWQP * u0;
#pragma unroll
        for (int c = 0; c < KT; ++c) {
            TKo[c] = (TKo[c] * vv[c]) * puw;
            TK0[c] = (TK0[c] * vv[c]) * pu0;
        }
    }

    // ---- final objective from converged Tp
    float obj;
    {
        float s[KT];
#pragma unroll
        for (int c = 0; c < KT; ++c) s[c] = TKo[c];
        sum16x5(s[0], s[1], s[2], s[3], s[4]);
        sum16x5(s[5], s[6], s[7], s[8], s[9]);
        v2f r0 = *(const v2f*)(ctp);
        v2f r1 = *(const v2f*)(ctp + 2);
        v2f r2 = *(const v2f*)(ctp + 4);
        v2f r3 = *(const v2f*)(ctp + 6);
        v2f r4 = *(const v2f*)(ctp + 8);
        float Cs, C0;
        {
            float a = r0.x * s[0],   b = r0.y * s[1];
            a = fmaf(r1.x, s[2], a); b = fmaf(r1.y, s[3], b);
            a = fmaf(r2.x, s[4], a); b = fmaf(r2.y, s[5], b);
            a = fmaf(r3.x, s[6], a); b = fmaf(r3.y, s[7], b);
            a = fmaf(r4.x, s[8], a); b = fmaf(r4.y, s[9], b);
            Cs = a + b;
            float q = r0.x * TK0[0],   d = r0.y * TK0[1];
            q = fmaf(r1.x, TK0[2], q); d = fmaf(r1.y, TK0[3], d);
            q = fmaf(r2.x, TK0[4], q); d = fmaf(r2.y, TK0[5], d);
            q = fmaf(r3.x, TK0[6], q); d = fmaf(r3.y, TK0[7], d);
            q = fmaf(r4.x, TK0[8], q); d = fmaf(r4.y, TK0[9], d);
            C0 = q + d;
        }
        float g0l = (16.f / 17.f) + ct2q - 2.f * Cs;
        float g1l = (1.f  / 17.f) + ct2q - 2.f * C0;
        float obj_own = 0.f, obj0 = 0.f;
#pragma unroll
        for (int c = 0; c < KT; ++c) {
            float G1c = __shfl(g1l, gbase + c, 64);
            float hM  = -EPSLN2 * FLOG2(myEM[c]);    // == 0.5*Mc_own[c]
            obj_own += TKo[c] * (hM + 0.5f * G1c);
            float G0c = __shfl(g0l, gbase + c, 64);
            float hM0 = -EPSLN2 * FLOG2(gEM0[c]);    // == 0.5*Mc0[c]
            obj0 += TK0[c] * (hM0 + 0.5f * G0c);
        }
        obj = sum16(obj_own) + obj0;
    }

    if (l == 0 && node < N) out[node * TT + w] = obj;
}

extern "C" void kernel_launch(void* const* d_in, const int* in_sizes, int n_in,
                              void* d_out, int out_size, void* d_ws, size_t ws_size,
                              hipStream_t stream) {
    const float* x    = (const float*)d_in[0];
    const int*   ei   = (const int*)d_in[1];
    const float* tmpl = (const float*)d_in[2];
    const float* tf   = (const float*)d_in[3];
    float* out = (float*)d_out;
    int N = in_sizes[0] / DD;
    int grid = (N + NPB - 1) / NPB;
    hipLaunchKernelGGL(ltfgw_kernel, dim3(grid), dim3(THREADS), 0, stream,
                       x, ei, tmpl, tf, out, N);
}

// Round 7
// 433.797 us; speedup vs baseline: 1.2194x; 1.2194x over previous
//
#include <hip/hip_runtime.h>

#define DEG 16
#define DD  128
#define KT  10      // template nodes (K)
#define TT  10      // templates
#define MM  17      // m = DEG+1
#define NPB 4       // nodes per block
#define THREADS 640 // 10 waves: wave w <-> template w
#define PITCH 132   // Fi row pitch in floats

#if __has_builtin(__builtin_amdgcn_exp2f)
#define FEXP2(x) __builtin_amdgcn_exp2f(x)
#else
#define FEXP2(x) exp2f(x)
#endif

#if __has_builtin(__builtin_amdgcn_rcpf)
#define FRCP(x) __builtin_amdgcn_rcpf(x)
#else
#define FRCP(x) (1.0f / (x))
#endif

#if __has_builtin(__builtin_amdgcn_logf)
#define FLOG2(x) __builtin_amdgcn_logf(x)
#else
#define FLOG2(x) __log2f(x)
#endif

// (1/EPS)*log2(e), EPS = 0.5
#define TWO_LOG2E 2.8853900817779268f
// log2(e): scale for the hoisted exp2 of 0.5*Mc
#define NLOG2E    1.4426950408889634f
// EPS*ln2 = 1/TWO_LOG2E: recovers 0.5*Mc from log2(eM)
#define EPSLN2    0.34657359027997264f
// QP = qw/pw = 17/10 folded into the 2-wide u-update: RQP = 1/QP = 10/17
#define RQP       0.5882352941176471f
// vv'' initial value = 1/QP
#define VV0       0.5882352941176471f
// pw*QP = (1/17)*(17/10) = 1/10 exactly
#define PWQP      0.1f

typedef float v2f __attribute__((ext_vector_type(2)));
typedef float v4f __attribute__((ext_vector_type(4)));

// packed fp32 fma, both mul operands in VGPRs
__device__ __forceinline__ v2f pk_fma(v2f a, v2f b, v2f c) {
    asm("v_pk_fma_f32 %0, %1, %2, %0" : "+v"(c) : "v"(a), "v"(b));
    return c;
}
// packed fp32 fma with a wave-uniform operand pinned to an SGPR pair:
// template data stays in scalar registers (s_load), offloading the VALU.
__device__ __forceinline__ v2f pk_fma_s(v2f a, v2f bs, v2f c) {
    asm("v_pk_fma_f32 %0, %1, %2, %0" : "+v"(c) : "v"(a), "s"(bs));
    return c;
}

// builtin-based 16-lane sum for the final objective
template <int CTRL>
__device__ __forceinline__ float dpp_add(float x) {
    union { float f; int i; } a, b;
    a.f = x;
    b.i = __builtin_amdgcn_update_dpp(0, a.i, CTRL, 0xF, 0xF, true);
    return x + b.f;
}
__device__ __forceinline__ float sum16(float t) {
    t = dpp_add<0xB1>(t);
    t = dpp_add<0x4E>(t);
    t = dpp_add<0x124>(t);
    t = dpp_add<0x128>(t);
    return t;
}

// hand-fused multi-value 16-lane butterflies (v_add_f32_dpp).
// VALU->DPP hazard needs 2 wait states: entry s_nop 1; interior spacing >=4.
#define _D(i, CTRL) "v_add_f32_dpp %" #i ", %" #i ", %" #i " " CTRL \
                    " row_mask:0xf bank_mask:0xf bound_ctrl:0\n\t"
#define _C1 "quad_perm:[1,0,3,2]"
#define _C2 "quad_perm:[2,3,0,1]"
#define _C3 "row_ror:4"
#define _C4 "row_ror:8"

__device__ __forceinline__ void sum16x6(float& a0, float& a1, float& a2,
                                        float& a3, float& a4, float& a5) {
    asm("s_nop 1\n\t"
        _D(0,_C1) _D(1,_C1) _D(2,_C1) _D(3,_C1) _D(4,_C1) _D(5,_C1)
        _D(0,_C2) _D(1,_C2) _D(2,_C2) _D(3,_C2) _D(4,_C2) _D(5,_C2)
        _D(0,_C3) _D(1,_C3) _D(2,_C3) _D(3,_C3) _D(4,_C3) _D(5,_C3)
        _D(0,_C4) _D(1,_C4) _D(2,_C4) _D(3,_C4) _D(4,_C4) _D(5,_C4)
        : "+v"(a0), "+v"(a1), "+v"(a2), "+v"(a3), "+v"(a4), "+v"(a5));
}

__device__ __forceinline__ void sum16x5(float& a0, float& a1, float& a2,
                                        float& a3, float& a4) {
    asm("s_nop 1\n\t"
        _D(0,_C1) _D(1,_C1) _D(2,_C1) _D(3,_C1) _D(4,_C1)
        _D(0,_C2) _D(1,_C2) _D(2,_C2) _D(3,_C2) _D(4,_C2)
        _D(0,_C3) _D(1,_C3) _D(2,_C3) _D(3,_C3) _D(4,_C3)
        _D(0,_C4) _D(1,_C4) _D(2,_C4) _D(3,_C4) _D(4,_C4)
        : "+v"(a0), "+v"(a1), "+v"(a2), "+v"(a3), "+v"(a4));
}

// Layout: wave w <-> template w; 64 lanes = 4 node-slots (p) x 16 lanes.
// Lane l owns row j=l+1; row 0 is register-replicated across the group.
// K=10 columns live in registers. TK arrays double as eK (inner loop) and
// Tp (outer boundary) -- never simultaneously live.
//
// OCCUPANCY KNOB (R7 experiment): launch_bounds min-waves/EU arg maps to a
// VGPR budget of ~256/waves. (,8) gave 32 VGPR + ~366MB spill traffic (R3,
// 427us); natural alloc gave 44-68 VGPR spill-free but low residency (R2/R6,
// 529-567us). (,4) targets 64 VGPR = this kernel's ~55-float hot live set:
// near-zero spills at clamp-class residency.
__global__ __launch_bounds__(THREADS, 4) void ltfgw_kernel(
    const float* __restrict__ x,      // [N,128]
    const int*   __restrict__ ei,     // edge_index[0], [N*DEG]
    const float* __restrict__ tmpl,   // [T,K,K]
    const float* __restrict__ tf,     // [T,K,128]
    float* __restrict__ out,          // [N,T]
    int N)
{
    constexpr int SLAB = MM * PITCH;     // 2244 floats per node
    __shared__ float sFi[NPB * SLAB];    // 35904 B

    const int tid = threadIdx.x;
    const int b0  = blockIdx.x * NPB;

    // ---- stage Fi
    {
        const int kq = tid & 31;
        for (int r = tid >> 5; r < NPB * MM; r += (THREADS >> 5)) {
            int p = r / MM, j = r % MM;
            int node = b0 + p;
            if (node < N) {
                int src = (j == 0) ? node : ei[node * DEG + (j - 1)];
                float4 v4 = *(const float4*)(x + (size_t)src * DD + kq * 4);
                *(float4*)(&sFi[p * SLAB + j * PITCH + kq * 4]) = v4;
            }
        }
    }
    __syncthreads();

    const int w     = tid >> 6;
    const int wu    = __builtin_amdgcn_readfirstlane(w);
    const int lane  = tid & 63;
    const int p     = lane >> 4;
    const int l     = lane & 15;
    const int gbase = lane & ~15;
    const int node  = b0 + p;

    const int cl = (l < KT) ? l : 0;
    // Ct row base for column cl (8B-aligned: 40-byte row stride)
    const float* ctp = tmpl + ((size_t)wu * KT + cl) * KT;

    // ---- ct2q = (Ct^2 @ q)[cl]
    float ct2q;
    {
        v2f r0 = *(const v2f*)(ctp);
        v2f r1 = *(const v2f*)(ctp + 2);
        v2f r2 = *(const v2f*)(ctp + 4);
        v2f r3 = *(const v2f*)(ctp + 6);
        v2f r4 = *(const v2f*)(ctp + 8);
        v2f acc = pk_fma(r0, r0, (v2f){0.f, 0.f});
        acc = pk_fma(r1, r1, acc);
        acc = pk_fma(r2, r2, acc);
        acc = pk_fma(r3, r3, acc);
        acc = pk_fma(r4, r4, acc);
        ct2q = (acc.x + acc.y) * (1.f / KT);
    }

    // ---- M main pass: own row (LDS) vs 10 template rows (SGPR via s_load)
    const float* myrow = &sFi[p * SLAB + (l + 1) * PITCH];
    const float* tw    = tf + (size_t)wu * KT * DD;   // wave-uniform
    v2f dotv[KT];
#pragma unroll
    for (int c = 0; c < KT; ++c) dotv[c] = (v2f){0.f, 0.f};
    v2f nrmv = (v2f){0.f, 0.f};
#pragma unroll 4
    for (int kk = 0; kk < DD; kk += 4) {
        v4f a4 = *(const v4f*)(myrow + kk);
        nrmv = pk_fma(a4.lo, a4.lo, nrmv);
        nrmv = pk_fma(a4.hi, a4.hi, nrmv);
#pragma unroll
        for (int c = 0; c < KT; ++c) {
            v4f f4 = *(const v4f*)(tw + c * DD + kk);   // uniform -> s_load
            dotv[c] = pk_fma_s(a4.lo, f4.lo, dotv[c]);
            dotv[c] = pk_fma_s(a4.hi, f4.hi, dotv[c]);
        }
    }
    float nrm_own = nrmv.x + nrmv.y;

    // ---- mini-pass: row 0 dots + template norms + row0 norm (k-distributed)
    float dot0[KT], nft[KT], n0p;
    {
        const float* row0 = &sFi[p * SLAB + 8 * l];
        v4f z0 = *(const v4f*)(row0);
        v4f z1 = *(const v4f*)(row0 + 4);
        v2f nn = pk_fma(z0.lo, z0.lo, (v2f){0.f, 0.f});
        nn = pk_fma(z0.hi, z0.hi, nn);
        nn = pk_fma(z1.lo, z1.lo, nn);
        nn = pk_fma(z1.hi, z1.hi, nn);
        n0p = nn.x + nn.y;
#pragma unroll
        for (int c = 0; c < KT; ++c) {
            const float* tr = tw + c * DD + 8 * l;   // lane-varying -> vector load
            v4f t0_ = *(const v4f*)(tr);
            v4f t1_ = *(const v4f*)(tr + 4);
            v2f d = pk_fma(z0.lo, t0_.lo, (v2f){0.f, 0.f});
            d = pk_fma(z0.hi, t0_.hi, d);
            d = pk_fma(z1.lo, t1_.lo, d);
            d = pk_fma(z1.hi, t1_.hi, d);
            dot0[c] = d.x + d.y;
            v2f nf = pk_fma(t0_.lo, t0_.lo, (v2f){0.f, 0.f});
            nf = pk_fma(t0_.hi, t0_.hi, nf);
            nf = pk_fma(t1_.lo, t1_.lo, nf);
            nf = pk_fma(t1_.hi, t1_.hi, nf);
            nft[c] = nf.x + nf.y;
        }
        sum16x6(dot0[0], dot0[1], dot0[2], dot0[3], dot0[4], dot0[5]);
        sum16x5(dot0[6], dot0[7], dot0[8], dot0[9], n0p);
        sum16x5(nft[0], nft[1], nft[2], nft[3], nft[4]);
        sum16x5(nft[5], nft[6], nft[7], nft[8], nft[9]);
    }

    // ---- hoisted mirror factors eM = exp2(-log2e * Mc)
    float eM_own[KT], eM0[KT];
#pragma unroll
    for (int c = 0; c < KT; ++c) {
        float mc0 = (n0p + nft[c] - 2.f * dot0[c]) * (1.f / DD);
        eM0[c] = FEXP2(-NLOG2E * mc0);
        float mcw = (nrm_own + nft[c] - 2.f * (dotv[c].x + dotv[c].y)) * (1.f / DD);
        eM_own[c] = FEXP2(-NLOG2E * mcw);
    }

    // ---- proximal Sinkhorn. TKo/TK0 hold Tp at outer boundaries, eK inside.
    float TKo[KT], TK0[KT], vv[KT];
#pragma unroll
    for (int c = 0; c < KT; ++c) {
        TKo[c] = 1.f / (MM * KT);
        TK0[c] = 1.f / (MM * KT);
    }
    float u_own = 0.f, u0 = 0.f;

#pragma unroll 1
    for (int outer = 0; outer < 5; ++outer) {
        // s[c] = 16-lane sum of Tp over neighbor rows
        float s[KT];
#pragma unroll
        for (int c = 0; c < KT; ++c) s[c] = TKo[c];
        sum16x5(s[0], s[1], s[2], s[3], s[4]);
        sum16x5(s[5], s[6], s[7], s[8], s[9]);

        // Ct row reload (L1-resident, 5x8B) + distributed Cs/C0 on column cl
        v2f r0 = *(const v2f*)(ctp);
        v2f r1 = *(const v2f*)(ctp + 2);
        v2f r2 = *(const v2f*)(ctp + 4);
        v2f r3 = *(const v2f*)(ctp + 6);
        v2f r4 = *(const v2f*)(ctp + 8);
        float Cs, C0;
        {
            float a = r0.x * s[0],   b = r0.y * s[1];
            a = fmaf(r1.x, s[2], a); b = fmaf(r1.y, s[3], b);
            a = fmaf(r2.x, s[4], a); b = fmaf(r2.y, s[5], b);
            a = fmaf(r3.x, s[6], a); b = fmaf(r3.y, s[7], b);
            a = fmaf(r4.x, s[8], a); b = fmaf(r4.y, s[9], b);
            Cs = a + b;
            float q = r0.x * TK0[0],   d = r0.y * TK0[1];
            q = fmaf(r1.x, TK0[2], q); d = fmaf(r1.y, TK0[3], d);
            q = fmaf(r2.x, TK0[4], q); d = fmaf(r2.y, TK0[5], d);
            q = fmaf(r3.x, TK0[6], q); d = fmaf(r3.y, TK0[7], d);
            q = fmaf(r4.x, TK0[8], q); d = fmaf(r4.y, TK0[9], d);
            C0 = q + d;
        }
        float e0 = FEXP2(-TWO_LOG2E * ((16.f / 17.f) + ct2q - 2.f * Cs));
        float e1 = FEXP2(-TWO_LOG2E * ((1.f  / 17.f) + ct2q - 2.f * C0));

        // Tp -> eK in place
#pragma unroll
        for (int c = 0; c < KT; ++c) {
            float E1c = __shfl(e1, gbase + c, 64);
            TKo[c] = TKo[c] * (eM_own[c] * E1c);
            float E0c = __shfl(e0, gbase + c, 64);
            TK0[c] = TK0[c] * (eM0[c] * E0c);
            vv[c] = VV0;   // vv'' = vv/QP
        }

        // 10 Sinkhorn iterations in the vv''-scaled domain:
        //   u = RQP * rcp(sum_c eK*vv'');  vv'' = rcp(sum_rows eK*u)
#pragma unroll 1
        for (int it = 0; it < 10; ++it) {
            float ra = TKo[0] * vv[0], rb = TKo[1] * vv[1];
            float qa = TK0[0] * vv[0], qb = TK0[1] * vv[1];
#pragma unroll
            for (int c = 2; c < KT; c += 2) {
                ra = fmaf(TKo[c],     vv[c],     ra);
                rb = fmaf(TKo[c + 1], vv[c + 1], rb);
                qa = fmaf(TK0[c],     vv[c],     qa);
                qb = fmaf(TK0[c + 1], vv[c + 1], qb);
            }
            u_own = RQP * FRCP(ra + rb);
            u0    = RQP * FRCP(qa + qb);
            float t[KT];
#pragma unroll
            for (int c = 0; c < KT; ++c) t[c] = TKo[c] * u_own;
            sum16x5(t[0], t[1], t[2], t[3], t[4]);
            sum16x5(t[5], t[6], t[7], t[8], t[9]);
#pragma unroll
            for (int c = 0; c < KT; ++c)
                vv[c] = FRCP(fmaf(TK0[c], u0, t[c]));
        }

        // eK -> Tp in place: Tp = (pw*QP) * u * eK * vv''
        float puw = PWQP * u_own, pu0 = PWQP * u0;
#pragma unroll
        for (int c = 0; c < KT; ++c) {
            TKo[c] = (TKo[c] * vv[c]) * puw;
            TK0[c] = (TK0[c] * vv[c]) * pu0;
        }
    }

    // ---- final objective from converged Tp
    float obj;
    {
        float s[KT];
#pragma unroll
        for (int c = 0; c < KT; ++c) s[c] = TKo[c];
        sum16x5(s[0], s[1], s[2], s[3], s[4]);
        sum16x5(s[5], s[6], s[7], s[8], s[9]);
        v2f r0 = *(const v2f*)(ctp);
        v2f r1 = *(const v2f*)(ctp + 2);
        v2f r2 = *(const v2f*)(ctp + 4);
        v2f r3 = *(const v2f*)(ctp + 6);
        v2f r4 = *(const v2f*)(ctp + 8);
        float Cs, C0;
        {
            float a = r0.x * s[0],   b = r0.y * s[1];
            a = fmaf(r1.x, s[2], a); b = fmaf(r1.y, s[3], b);
            a = fmaf(r2.x, s[4], a); b = fmaf(r2.y, s[5], b);
            a = fmaf(r3.x, s[6], a); b = fmaf(r3.y, s[7], b);
            a = fmaf(r4.x, s[8], a); b = fmaf(r4.y, s[9], b);
            Cs = a + b;
            float q = r0.x * TK0[0],   d = r0.y * TK0[1];
            q = fmaf(r1.x, TK0[2], q); d = fmaf(r1.y, TK0[3], d);
            q = fmaf(r2.x, TK0[4], q); d = fmaf(r2.y, TK0[5], d);
            q = fmaf(r3.x, TK0[6], q); d = fmaf(r3.y, TK0[7], d);
            q = fmaf(r4.x, TK0[8], q); d = fmaf(r4.y, TK0[9], d);
            C0 = q + d;
        }
        float g0l = (16.f / 17.f) + ct2q - 2.f * Cs;
        float g1l = (1.f  / 17.f) + ct2q - 2.f * C0;
        float obj_own = 0.f, obj0 = 0.f;
#pragma unroll
        for (int c = 0; c < KT; ++c) {
            float G1c = __shfl(g1l, gbase + c, 64);
            float hM  = -EPSLN2 * FLOG2(eM_own[c]);    // == 0.5*Mc_own[c]
            obj_own += TKo[c] * (hM + 0.5f * G1c);
            float G0c = __shfl(g0l, gbase + c, 64);
            float hM0 = -EPSLN2 * FLOG2(eM0[c]);       // == 0.5*Mc0[c]
            obj0 += TK0[c] * (hM0 + 0.5f * G0c);
        }
        obj = sum16(obj_own) + obj0;
    }

    if (l == 0 && node < N) out[node * TT + w] = obj;
}

extern "C" void kernel_launch(void* const* d_in, const int* in_sizes, int n_in,
                              void* d_out, int out_size, void* d_ws, size_t ws_size,
                              hipStream_t stream) {
    const float* x    = (const float*)d_in[0];
    const int*   ei   = (const int*)d_in[1];
    const float* tmpl = (const float*)d_in[2];
    const float* tf   = (const float*)d_in[3];
    float* out = (float*)d_out;
    int N = in_sizes[0] / DD;
    int grid = (N + NPB - 1) / NPB;
    hipLaunchKernelGGL(ltfgw_kernel, dim3(grid), dim3(THREADS), 0, stream,
                       x, ei, tmpl, tf, out, N);
}